// Round 5
// baseline (267.424 us; speedup 1.0000x reference)
//
#include <hip/hip_runtime.h>
#include <hip/hip_bf16.h>

#define L2E 1.4426950408889634f
#define LN2 0.6931471805599453f

__device__ __forceinline__ float fexp2(float x) { return __builtin_amdgcn_exp2f(x); }
__device__ __forceinline__ float flog2(float x) { return __builtin_amdgcn_logf(x); }
__device__ __forceinline__ int uniform(int x) { return __builtin_amdgcn_readfirstlane(x); }
__device__ __forceinline__ float sigmoidf_(float v) { return 1.f / (1.f + fexp2(-v * L2E)); }
__device__ __forceinline__ float softplusf_(float t) {
    return (t > 20.f) ? t : LN2 * flog2(1.f + fexp2(t * L2E));
}

// ---------------- workspace layout (floats) ----------------
constexpr size_t O_M   = 0;          // [32][1024] LN mean
constexpr size_t O_RS  = 32768;      // [32][1024] LN rstd
constexpr size_t O_G   = 65536;      // [32][128][1024] xi, later y_ssm
constexpr size_t O_Z   = 4259840;    // [32][128][1024] z
constexpr size_t O_XC  = 8454144;    // [32][128][1024] conv+silu out
constexpr size_t O_BM  = 12648448;   // [32][16][1024]
constexpr size_t O_CM  = 13172736;   // [32][16][1024]
constexpr size_t O_DTP = 13697024;   // [32][4][1024] dt-proj pre-softplus (planes)
constexpr size_t O_HP  = 13828096;   // [32][32][2][2048] per-chunk P(->h_init) and E

// ================= K1: LN + in-proj GEMM W[256,64] @ XN[64,1024] =================
// grid 2048 = 32 seq * 4 jb * 16 pb; block 256 = 4 waves; wave handles 16 j's x 64 p.
__global__ __launch_bounds__(256) void k1_ln_inproj(
    const float* __restrict__ x0, const float* __restrict__ x1,
    const float* __restrict__ x2, const float* __restrict__ x3,
    const float* __restrict__ win,
    const float* __restrict__ g1, const float* __restrict__ be1,
    const float* __restrict__ g2, const float* __restrict__ be2,
    const float* __restrict__ g3, const float* __restrict__ be3,
    const float* __restrict__ g4, const float* __restrict__ be4,
    float* __restrict__ ws)
{
    __shared__ float sX[64 * 68];
    __shared__ float sPs[256], sPq[256];
    __shared__ float sM[64], sR[64];
    int bid = blockIdx.x;
    int seq = bid >> 6, jb = (bid >> 4) & 3, pb = bid & 15;
    int branch = seq >> 3, b = seq & 7;
    int tid = threadIdx.x;
    int lane = tid & 63;
    int wq = uniform(tid >> 6);
    const float* xin = (branch==0)?x0:(branch==1)?x1:(branch==2)?x2:x3;
    const float* gam = (branch==0)?g1:(branch==1)?g2:(branch==2)?g3:g4;
    const float* bet = (branch==0)?be1:(branch==1)?be2:(branch==2)?be3:be4;
    const float* xb = xin + (size_t)b * 65536 + pb * 64;

    // stage X tile [64 c][64 p] via float4
#pragma unroll
    for (int k = 0; k < 4; ++k) {
        int i = tid + k * 256;
        int c = i >> 4, p4 = (i & 15) * 4;
        *(float4*)&sX[c * 68 + p4] = *(const float4*)&xb[(size_t)c * 1024 + p4];
    }
    __syncthreads();
    // LN stats: two-level reduce, all threads active
    {
        float s = 0.f, q = 0.f;
#pragma unroll
        for (int cc = 0; cc < 16; ++cc) {
            float v = sX[(wq * 16 + cc) * 68 + lane];
            s += v; q += v * v;
        }
        sPs[wq * 64 + lane] = s; sPq[wq * 64 + lane] = q;
    }
    __syncthreads();
    if (tid < 64) {
        float ss = sPs[tid] + sPs[64 + tid] + sPs[128 + tid] + sPs[192 + tid];
        float qq = sPq[tid] + sPq[64 + tid] + sPq[128 + tid] + sPq[192 + tid];
        float mean = ss * (1.f/64.f);
        float var  = qq * (1.f/64.f) - mean * mean;
        float rs   = rsqrtf(var + 1e-5f);
        sM[tid] = mean; sR[tid] = rs;
        if (jb == 0) {
            ws[O_M  + (size_t)seq * 1024 + pb * 64 + tid] = mean;
            ws[O_RS + (size_t)seq * 1024 + pb * 64 + tid] = rs;
        }
    }
    __syncthreads();
    {
        float mean = sM[lane], rs = sR[lane];
#pragma unroll
        for (int cc = 0; cc < 16; ++cc) {
            int c = wq * 16 + cc;                       // uniform -> gam/bet s_load
            float v = sX[c * 68 + lane];
            sX[c * 68 + lane] = (v - mean) * rs * gam[c] + bet[c];
        }
    }
    __syncthreads();
    // GEMM: 16 j per thread, K=64 in chunks of 4; weights via s_load
    float acc[16];
#pragma unroll
    for (int jj = 0; jj < 16; ++jj) acc[jj] = 0.f;
    int jbase = jb * 64 + wq * 16;                      // uniform
#pragma unroll 4
    for (int c4 = 0; c4 < 16; ++c4) {
        float xv0 = sX[(c4*4+0) * 68 + lane];
        float xv1 = sX[(c4*4+1) * 68 + lane];
        float xv2 = sX[(c4*4+2) * 68 + lane];
        float xv3 = sX[(c4*4+3) * 68 + lane];
#pragma unroll
        for (int jj = 0; jj < 16; ++jj) {
            float4 w4 = *(const float4*)&win[(size_t)(jbase + jj) * 64 + c4 * 4];
            acc[jj] += xv0*w4.x + xv1*w4.y + xv2*w4.z + xv3*w4.w;
        }
    }
    float* xi = ws + O_G + (size_t)seq * 131072;
    float* zz = ws + O_Z + (size_t)seq * 131072;
    int col = pb * 64 + lane;
#pragma unroll
    for (int jj = 0; jj < 16; ++jj) {
        int j = jbase + jj;
        if (j < 128) xi[(size_t)j * 1024 + col] = acc[jj];
        else         zz[(size_t)(j - 128) * 1024 + col] = acc[jj];
    }
}

// ================= K2: conv4 + SiLU (in-place LDS) + x-proj(128->36) =================
// grid 512 = 32 seq * 16 ptile; block 256.
__global__ __launch_bounds__(256) void k2_conv_proj(
    const float* __restrict__ wconv, const float* __restrict__ bconv,
    const float* __restrict__ wxp, float* __restrict__ ws)
{
    __shared__ float sXi[128 * 72];   // [d][4 halo + 64 p], pad 72
    int bid = blockIdx.x;
    int seq = bid >> 4, ptile = bid & 15;
    int tid = threadIdx.x;
    int lane = tid & 63;
    int wq = uniform(tid >> 6);
    int p0 = ptile * 64;
    const float* xig = ws + O_G  + (size_t)seq * 131072 + p0;
    float*       xcg = ws + O_XC + (size_t)seq * 131072 + p0;

    // stage main tile via float4
#pragma unroll
    for (int k = 0; k < 8; ++k) {
        int i = tid + k * 256;
        int d = i >> 4, p4 = (i & 15) * 4;
        *(float4*)&sXi[d * 72 + 4 + p4] = *(const float4*)&xig[(size_t)d * 1024 + p4];
    }
    // halo (4 cols left)
    if (tid < 128) {
        float4 hv = (ptile > 0) ? *(const float4*)&xig[(size_t)tid * 1024 - 4]
                                : make_float4(0.f, 0.f, 0.f, 0.f);
        *(float4*)&sXi[tid * 72] = hv;
    }
    __syncthreads();
    // conv + silu, in place (rows wave-private; lockstep read-before-write)
    for (int dd = 0; dd < 32; ++dd) {
        int d = wq * 32 + dd;                               // uniform
        float4 wc = *(const float4*)&wconv[d * 4];          // s_load
        float v = bconv[d];
        int base = d * 72 + 4 + lane;
        float a3 = sXi[base - 3], a2v = sXi[base - 2], a1 = sXi[base - 1], a0 = sXi[base];
        v += a3*wc.x + a2v*wc.y + a1*wc.z + a0*wc.w;
        v = v * sigmoidf_(v);
        sXi[base] = v;
        xcg[(size_t)d * 1024 + lane] = v;
    }
    __syncthreads();
    // proj GEMM: 9 j per wave-thread, K=128, weights via s_load
    float acc[9];
#pragma unroll
    for (int jj = 0; jj < 9; ++jj) acc[jj] = 0.f;
    int jbase = wq * 9;                                     // uniform
#pragma unroll 4
    for (int c4 = 0; c4 < 32; ++c4) {
        float xv0 = sXi[(c4*4+0) * 72 + 4 + lane];
        float xv1 = sXi[(c4*4+1) * 72 + 4 + lane];
        float xv2 = sXi[(c4*4+2) * 72 + 4 + lane];
        float xv3 = sXi[(c4*4+3) * 72 + 4 + lane];
#pragma unroll
        for (int jj = 0; jj < 9; ++jj) {
            float4 w4 = *(const float4*)&wxp[(size_t)(jbase + jj) * 128 + c4 * 4];
            acc[jj] += xv0*w4.x + xv1*w4.y + xv2*w4.z + xv3*w4.w;
        }
    }
#pragma unroll
    for (int jj = 0; jj < 9; ++jj) {
        int j = jbase + jj;                                 // uniform
        float v = acc[jj];
        if (j < 4)       ws[O_DTP + ((size_t)seq * 4 + j) * 1024 + p0 + lane] = v;
        else if (j < 20) ws[O_BM + (size_t)seq * 16384 + (size_t)(j - 4)  * 1024 + p0 + lane] = v;
        else             ws[O_CM + (size_t)seq * 16384 + (size_t)(j - 20) * 1024 + p0 + lane] = v;
    }
}

// ================= K3: chunk-parallel scan, 32 chunks x 32 steps =================
__device__ __forceinline__ void k3_a2(const float* alog, int d0, int s0, float* a2) {
    float4 a0 = *(const float4*)(alog + d0 * 16 + s0);
    float4 a1 = *(const float4*)(alog + (d0 + 1) * 16 + s0);
    a2[0] = -fexp2(a0.x * L2E) * L2E; a2[1] = -fexp2(a0.y * L2E) * L2E;
    a2[2] = -fexp2(a0.z * L2E) * L2E; a2[3] = -fexp2(a0.w * L2E) * L2E;
    a2[4] = -fexp2(a1.x * L2E) * L2E; a2[5] = -fexp2(a1.y * L2E) * L2E;
    a2[6] = -fexp2(a1.z * L2E) * L2E; a2[7] = -fexp2(a1.w * L2E) * L2E;
}

// shared staging: xc tile, dt tile (softplus precomputed once), B tile
__device__ __forceinline__ void k3_stage(const float* __restrict__ wdt,
                                         const float* __restrict__ bdt,
                                         const float* __restrict__ ws,
                                         int seq, int lb, int tid,
                                         float* sXC, float* sDt, float* sDtp4, float* sB)
{
    const float* xcg = ws + O_XC + (size_t)seq * 131072;
    const float* Bmg = ws + O_BM + (size_t)seq * 16384;
    const float* dtp = ws + O_DTP + (size_t)seq * 4096;
#pragma unroll
    for (int k = 0; k < 16; ++k) {
        int i = tid + k * 256;
        int d = i >> 5, li = i & 31;
        sXC[d * 33 + li] = xcg[(size_t)d * 1024 + lb + li];
    }
#pragma unroll
    for (int k = 0; k < 2; ++k) {
        int i = tid + k * 256;
        int s = i >> 5, li = i & 31;
        sB[li * 16 + s] = Bmg[(size_t)s * 1024 + lb + li];
    }
    if (tid < 128) {
        int jj = tid >> 5, li = tid & 31;
        sDtp4[jj * 33 + li] = dtp[(size_t)jj * 1024 + lb + li];
    }
    __syncthreads();
    // dt = softplus(dtp @ wdt^T + bdt), shared across the block (4x dedup)
#pragma unroll
    for (int k = 0; k < 16; ++k) {
        int i = tid + k * 256;
        int d = i >> 5, li = i & 31;
        float4 wv = *(const float4*)&wdt[d * 4];
        float t = bdt[d] + sDtp4[0*33+li]*wv.x + sDtp4[1*33+li]*wv.y
                         + sDtp4[2*33+li]*wv.z + sDtp4[3*33+li]*wv.w;
        sDt[d * 33 + li] = softplusf_(t);
    }
    __syncthreads();
}

// phase A: local scan (h0=0); emit per-chunk P = exp2(a2*sum_dt) and end E
__global__ __launch_bounds__(256) void k3a_scan(const float* __restrict__ wdt,
                                                const float* __restrict__ bdt,
                                                const float* __restrict__ alog,
                                                float* __restrict__ ws)
{
    __shared__ float sXC[128 * 33];
    __shared__ float sDt[128 * 33];
    __shared__ float sDtp4[4 * 33];
    __shared__ __align__(16) float sB[32 * 16];
    int bid = blockIdx.x;
    int seq = bid >> 5, ch = bid & 31;
    int lb = ch * 32;
    int tid = threadIdx.x;
    int d0 = (tid >> 2) * 2, s0 = (tid & 3) * 4;

    float a2[8];
    k3_a2(alog, d0, s0, a2);
    k3_stage(wdt, bdt, ws, seq, lb, tid, sXC, sDt, sDtp4, sB);

    float h[8];
#pragma unroll
    for (int i = 0; i < 8; ++i) h[i] = 0.f;
    float sdt0 = 0.f, sdt1 = 0.f;
    for (int li = 0; li < 32; ++li) {
        float dt0 = sDt[d0 * 33 + li], dt1 = sDt[(d0 + 1) * 33 + li];
        float dx0 = dt0 * sXC[d0 * 33 + li], dx1 = dt1 * sXC[(d0 + 1) * 33 + li];
        float4 Bv = *(const float4*)&sB[li * 16 + s0];
        float bv[4] = {Bv.x, Bv.y, Bv.z, Bv.w};
        sdt0 += dt0; sdt1 += dt1;
#pragma unroll
        for (int ss = 0; ss < 4; ++ss) {
            h[ss]     = fexp2(dt0 * a2[ss])     * h[ss]     + dx0 * bv[ss];
            h[4 + ss] = fexp2(dt1 * a2[4 + ss]) * h[4 + ss] + dx1 * bv[ss];
        }
    }
    float* hp = ws + O_HP + (size_t)(seq * 32 + ch) * 4096;
#pragma unroll
    for (int ss = 0; ss < 4; ++ss) {
        hp[d0 * 16 + s0 + ss]              = fexp2(a2[ss] * sdt0);
        hp[(d0 + 1) * 16 + s0 + ss]        = fexp2(a2[4 + ss] * sdt1);
        hp[2048 + d0 * 16 + s0 + ss]       = h[ss];
        hp[2048 + (d0 + 1) * 16 + s0 + ss] = h[4 + ss];
    }
}

// phase B: per-seq sequential prefix compose; h_init overwrites P slot
__global__ __launch_bounds__(256) void k3b_compose(float* __restrict__ ws)
{
    int seq = blockIdx.x;
    int tid = threadIdx.x;
    int d0 = (tid >> 2) * 2, s0 = (tid & 3) * 4;
    int i0 = d0 * 16 + s0, i1 = (d0 + 1) * 16 + s0;
    float h[8];
#pragma unroll
    for (int i = 0; i < 8; ++i) h[i] = 0.f;
    float* hpb = ws + O_HP + (size_t)seq * 32 * 4096;
    for (int c = 0; c < 32; ++c) {
        float* hp = hpb + (size_t)c * 4096;
        float4 P0 = *(const float4*)&hp[i0];
        float4 P1 = *(const float4*)&hp[i1];
        float4 E0 = *(const float4*)&hp[2048 + i0];
        float4 E1 = *(const float4*)&hp[2048 + i1];
        *(float4*)&hp[i0] = make_float4(h[0], h[1], h[2], h[3]);
        *(float4*)&hp[i1] = make_float4(h[4], h[5], h[6], h[7]);
        h[0] = P0.x * h[0] + E0.x; h[1] = P0.y * h[1] + E0.y;
        h[2] = P0.z * h[2] + E0.z; h[3] = P0.w * h[3] + E0.w;
        h[4] = P1.x * h[4] + E1.x; h[5] = P1.y * h[5] + E1.y;
        h[6] = P1.z * h[6] + E1.z; h[7] = P1.w * h[7] + E1.w;
    }
}

// phase C: rescan from h_init; y written back into sXC (lockstep-safe), then out
__global__ __launch_bounds__(256) void k3c_scan_y(const float* __restrict__ wdt,
                                                  const float* __restrict__ bdt,
                                                  const float* __restrict__ alog,
                                                  float* __restrict__ ws)
{
    __shared__ float sXC[128 * 33];
    __shared__ float sDt[128 * 33];
    __shared__ float sDtp4[4 * 33];
    __shared__ __align__(16) float sB[32 * 16];
    __shared__ __align__(16) float sC[32 * 16];
    int bid = blockIdx.x;
    int seq = bid >> 5, ch = bid & 31;
    int lb = ch * 32;
    int tid = threadIdx.x;
    int sq = tid & 3;
    int d0 = (tid >> 2) * 2, s0 = sq * 4;

    float a2[8];
    k3_a2(alog, d0, s0, a2);
    // extra C staging alongside the shared staging
    {
        const float* Cmg = ws + O_CM + (size_t)seq * 16384;
#pragma unroll
        for (int k = 0; k < 2; ++k) {
            int i = tid + k * 256;
            int s = i >> 5, li = i & 31;
            sC[li * 16 + s] = Cmg[(size_t)s * 1024 + lb + li];
        }
    }
    k3_stage(wdt, bdt, ws, seq, lb, tid, sXC, sDt, sDtp4, sB);

    const float* hp = ws + O_HP + (size_t)(seq * 32 + ch) * 4096;
    float4 H0 = *(const float4*)&hp[d0 * 16 + s0];
    float4 H1 = *(const float4*)&hp[(d0 + 1) * 16 + s0];
    float h[8] = {H0.x, H0.y, H0.z, H0.w, H1.x, H1.y, H1.z, H1.w};

    for (int li = 0; li < 32; ++li) {
        float dt0 = sDt[d0 * 33 + li], dt1 = sDt[(d0 + 1) * 33 + li];
        float dx0 = dt0 * sXC[d0 * 33 + li], dx1 = dt1 * sXC[(d0 + 1) * 33 + li];
        float4 Bv = *(const float4*)&sB[li * 16 + s0];
        float4 Cv = *(const float4*)&sC[li * 16 + s0];
        float bv[4] = {Bv.x, Bv.y, Bv.z, Bv.w};
        float cv[4] = {Cv.x, Cv.y, Cv.z, Cv.w};
        float acc0 = 0.f, acc1 = 0.f;
#pragma unroll
        for (int ss = 0; ss < 4; ++ss) {
            h[ss] = fexp2(dt0 * a2[ss]) * h[ss] + dx0 * bv[ss];
            acc0 += h[ss] * cv[ss];
            h[4 + ss] = fexp2(dt1 * a2[4 + ss]) * h[4 + ss] + dx1 * bv[ss];
            acc1 += h[4 + ss] * cv[ss];
        }
        acc0 += __shfl_xor(acc0, 1); acc0 += __shfl_xor(acc0, 2);
        acc1 += __shfl_xor(acc1, 1); acc1 += __shfl_xor(acc1, 2);
        if (sq == 0) {                       // overwrite consumed xc slot with y
            sXC[d0 * 33 + li]       = acc0;
            sXC[(d0 + 1) * 33 + li] = acc1;
        }
    }
    __syncthreads();
    float* gg = ws + O_G + (size_t)seq * 131072;
#pragma unroll
    for (int k = 0; k < 16; ++k) {
        int i = tid + k * 256;
        int d = i >> 5, li = i & 31;
        gg[(size_t)d * 1024 + lb + li] = sXC[d * 33 + li];
    }
}

// ================= K4: gate + out-proj Wout[64,128] + skip =================
// grid 512 = 32 seq * 16 pb; block 256; wave handles 16 c x 64 p, K=128.
__global__ __launch_bounds__(256) void k4_out(
    const float* __restrict__ x0, const float* __restrict__ x1,
    const float* __restrict__ x2, const float* __restrict__ x3,
    const float* __restrict__ g1, const float* __restrict__ be1,
    const float* __restrict__ g2, const float* __restrict__ be2,
    const float* __restrict__ g3, const float* __restrict__ be3,
    const float* __restrict__ g4, const float* __restrict__ be4,
    const float* __restrict__ dpar, const float* __restrict__ woutp,
    const float* __restrict__ skipp, const float* __restrict__ ws,
    float* __restrict__ out)
{
    __shared__ float sG[128 * 68];
    int bid = blockIdx.x;
    int seq = bid >> 4, pb = bid & 15;
    int branch = seq >> 3, b = seq & 7;
    int tid = threadIdx.x;
    int lane = tid & 63;
    int wq = uniform(tid >> 6);
    const float* ys = ws + O_G  + (size_t)seq * 131072 + pb * 64;
    const float* zz = ws + O_Z  + (size_t)seq * 131072 + pb * 64;
    const float* xc = ws + O_XC + (size_t)seq * 131072 + pb * 64;

    // gating: g = (y + D*xc) * silu(z), float4 staged
#pragma unroll
    for (int k = 0; k < 8; ++k) {
        int i = tid + k * 256;
        int d = i >> 4, p4 = (i & 15) * 4;
        size_t off = (size_t)d * 1024 + p4;
        float4 y4 = *(const float4*)&ys[off];
        float4 z4 = *(const float4*)&zz[off];
        float4 c4 = *(const float4*)&xc[off];
        float Dd = dpar[d];
        float4 g4v;
        g4v.x = (y4.x + Dd * c4.x) * (z4.x * sigmoidf_(z4.x));
        g4v.y = (y4.y + Dd * c4.y) * (z4.y * sigmoidf_(z4.y));
        g4v.z = (y4.z + Dd * c4.z) * (z4.z * sigmoidf_(z4.z));
        g4v.w = (y4.w + Dd * c4.w) * (z4.w * sigmoidf_(z4.w));
        *(float4*)&sG[d * 68 + p4] = g4v;
    }
    __syncthreads();
    // GEMM: 16 c per thread, K=128, weights via s_load
    float acc[16];
#pragma unroll
    for (int cc = 0; cc < 16; ++cc) acc[cc] = 0.f;
    int cbase = wq * 16;                                   // uniform
#pragma unroll 4
    for (int d4 = 0; d4 < 32; ++d4) {
        float xv0 = sG[(d4*4+0) * 68 + lane];
        float xv1 = sG[(d4*4+1) * 68 + lane];
        float xv2 = sG[(d4*4+2) * 68 + lane];
        float xv3 = sG[(d4*4+3) * 68 + lane];
#pragma unroll
        for (int cc = 0; cc < 16; ++cc) {
            float4 w4 = *(const float4*)&woutp[(size_t)(cbase + cc) * 128 + d4 * 4];
            acc[cc] += xv0*w4.x + xv1*w4.y + xv2*w4.z + xv3*w4.w;
        }
    }
    // epilogue: + skip * xn (recomputed)
    const float* xin = (branch==0)?x0:(branch==1)?x1:(branch==2)?x2:x3;
    const float* gam = (branch==0)?g1:(branch==1)?g2:(branch==2)?g3:g4;
    const float* bet = (branch==0)?be1:(branch==1)?be2:(branch==2)?be3:be4;
    const float* xb = xin + (size_t)b * 65536 + pb * 64;
    int col = pb * 64 + lane;
    float skipv = skipp[0];
    float mean = ws[O_M  + (size_t)seq * 1024 + col];
    float rs   = ws[O_RS + (size_t)seq * 1024 + col];
#pragma unroll
    for (int cc = 0; cc < 16; ++cc) {
        int c = cbase + cc;                                // uniform
        float xv = xb[(size_t)c * 1024 + lane];
        float xn = (xv - mean) * rs * gam[c] + bet[c];
        out[((size_t)b * 256 + branch * 64 + c) * 1024 + col] = acc[cc] + skipv * xn;
    }
}

// ---------------- launch ----------------
extern "C" void kernel_launch(void* const* d_in, const int* in_sizes, int n_in,
                              void* d_out, int out_size, void* d_ws, size_t ws_size,
                              hipStream_t stream) {
    float* ws = (float*)d_ws;
    auto f = [&](int i) { return (const float*)d_in[i]; };
    hipLaunchKernelGGL(k1_ln_inproj, dim3(2048), dim3(256), 0, stream,
        f(0), f(1), f(2), f(3), f(13),
        f(4), f(5), f(6), f(7), f(8), f(9), f(10), f(11), ws);
    hipLaunchKernelGGL(k2_conv_proj, dim3(512), dim3(256), 0, stream,
        f(14), f(15), f(16), ws);
    hipLaunchKernelGGL(k3a_scan, dim3(1024), dim3(256), 0, stream, f(17), f(18), f(19), ws);
    hipLaunchKernelGGL(k3b_compose, dim3(32), dim3(256), 0, stream, ws);
    hipLaunchKernelGGL(k3c_scan_y, dim3(1024), dim3(256), 0, stream, f(17), f(18), f(19), ws);
    hipLaunchKernelGGL(k4_out, dim3(512), dim3(256), 0, stream,
        f(0), f(1), f(2), f(3),
        f(4), f(5), f(6), f(7), f(8), f(9), f(10), f(11),
        f(20), f(21), f(12), ws, (float*)d_out);
}

// Round 6
// 253.912 us; speedup vs baseline: 1.0532x; 1.0532x over previous
//
#include <hip/hip_runtime.h>
#include <hip/hip_bf16.h>

#define L2E 1.4426950408889634f
#define LN2 0.6931471805599453f

__device__ __forceinline__ float fexp2(float x) { return __builtin_amdgcn_exp2f(x); }
__device__ __forceinline__ float flog2(float x) { return __builtin_amdgcn_logf(x); }
__device__ __forceinline__ int uniform(int x) { return __builtin_amdgcn_readfirstlane(x); }
__device__ __forceinline__ float sigmoidf_(float v) { return 1.f / (1.f + fexp2(-v * L2E)); }
__device__ __forceinline__ float softplusf_(float t) {
    return (t > 20.f) ? t : LN2 * flog2(1.f + fexp2(t * L2E));
}

// ---------------- workspace layout (floats) ----------------
constexpr size_t O_M   = 0;          // [32][1024] LN mean
constexpr size_t O_RS  = 32768;      // [32][1024] LN rstd
constexpr size_t O_Z   = 65536;      // [32][128][1024] z
constexpr size_t O_XC  = 4259840;    // [32][128][1024] conv+silu out
constexpr size_t O_BM  = 8454144;    // [32][16][1024]
constexpr size_t O_CM  = 8978432;    // [32][16][1024]
constexpr size_t O_DTP = 9502720;    // [32][4][1024] dt-proj pre-softplus planes
constexpr size_t O_HP  = 9633792;    // [32][32][2][2048] per-chunk P(->h_init) and E

// ================= kA: LN + in-proj + conv/SiLU + x-proj (fused) =================
// grid 512 = 32 seq * 16 ptile (64 cols); block 256 = 4 waves.
// LDS col indexing: 0..63 = main cols p0..p0+63; 64..66 = halo cols p0-3..p0-1.
__global__ __launch_bounds__(256) void kA_front(
    const float* __restrict__ x0, const float* __restrict__ x1,
    const float* __restrict__ x2, const float* __restrict__ x3,
    const float* __restrict__ win,
    const float* __restrict__ g1, const float* __restrict__ be1,
    const float* __restrict__ g2, const float* __restrict__ be2,
    const float* __restrict__ g3, const float* __restrict__ be3,
    const float* __restrict__ g4, const float* __restrict__ be4,
    const float* __restrict__ wconv, const float* __restrict__ bconv,
    const float* __restrict__ wxp, float* __restrict__ ws)
{
    __shared__ float sX[64 * 68];     // xn staging [c][col]
    __shared__ float sXI[128 * 68];   // xi -> xc [d][col]
    __shared__ float sM[68], sR[68];
    int bid = blockIdx.x;
    int seq = bid >> 4, ptile = bid & 15;
    int branch = seq >> 3, b = seq & 7;
    int tid = threadIdx.x;
    int lane = tid & 63;
    int wq = uniform(tid >> 6);
    int p0 = ptile * 64;
    const float* xin = (branch==0)?x0:(branch==1)?x1:(branch==2)?x2:x3;
    const float* gam = (branch==0)?g1:(branch==1)?g2:(branch==2)?g3:g4;
    const float* bet = (branch==0)?be1:(branch==1)?be2:(branch==2)?be3:be4;
    const float* xb = xin + (size_t)b * 65536;

    // ---- stage raw x: main 64 cols (float4) + 3 halo cols ----
#pragma unroll
    for (int k = 0; k < 4; ++k) {
        int i = tid + k * 256;
        int c = i >> 4, p4 = (i & 15) * 4;
        *(float4*)&sX[c * 68 + p4] = *(const float4*)&xb[(size_t)c * 1024 + p0 + p4];
    }
    if (ptile > 0) {
        int hc = tid & 3, c = tid >> 2;
        if (hc < 3) sX[c * 68 + 64 + hc] = xb[(size_t)c * 1024 + p0 - 3 + hc];
    }
    __syncthreads();
    // ---- LN stats per column ----
    int ncols = (ptile > 0) ? 67 : 64;
    if (tid < ncols) {
        float s = 0.f, q = 0.f;
#pragma unroll
        for (int c = 0; c < 64; ++c) {
            float v = sX[c * 68 + tid];
            s += v; q += v * v;
        }
        float mean = s * (1.f/64.f);
        float var  = q * (1.f/64.f) - mean * mean;
        float rs   = rsqrtf(var + 1e-5f);
        sM[tid] = mean; sR[tid] = rs;
        if (tid < 64) {
            ws[O_M  + (size_t)seq * 1024 + p0 + tid] = mean;
            ws[O_RS + (size_t)seq * 1024 + p0 + tid] = rs;
        }
    }
    __syncthreads();
    // ---- normalize: main (c uniform per wave) + halo ----
#pragma unroll
    for (int k = 0; k < 16; ++k) {
        int c = wq + k * 4;                              // uniform
        float v = sX[c * 68 + lane];
        sX[c * 68 + lane] = (v - sM[lane]) * sR[lane] * gam[c] + bet[c];
    }
    if (ptile > 0) {
        int hc = tid & 3, c = tid >> 2;
        if (hc < 3) {
            int col = 64 + hc;
            float v = sX[c * 68 + col];
            sX[c * 68 + col] = (v - sM[col]) * sR[col] * gam[c] + bet[c];
        }
    }
    __syncthreads();
    // ---- in-proj main: 8 passes x 8 j per thread (K=64); xi->LDS, z->global ----
    float* zz = ws + O_Z + (size_t)seq * 131072;
    for (int pass = 0; pass < 8; ++pass) {
        int jb0 = pass * 32 + wq * 8;                    // uniform
        float acc[8];
#pragma unroll
        for (int jj = 0; jj < 8; ++jj) acc[jj] = 0.f;
#pragma unroll 2
        for (int c4 = 0; c4 < 16; ++c4) {
            float xv0 = sX[(c4*4+0) * 68 + lane];
            float xv1 = sX[(c4*4+1) * 68 + lane];
            float xv2 = sX[(c4*4+2) * 68 + lane];
            float xv3 = sX[(c4*4+3) * 68 + lane];
#pragma unroll
            for (int jj = 0; jj < 8; ++jj) {
                float4 w4 = *(const float4*)&win[(size_t)(jb0 + jj) * 64 + c4 * 4];
                acc[jj] += xv0*w4.x + xv1*w4.y + xv2*w4.z + xv3*w4.w;
            }
        }
#pragma unroll
        for (int jj = 0; jj < 8; ++jj) {
            int j = jb0 + jj;
            if (j < 128) sXI[j * 68 + lane] = acc[jj];
            else         zz[(size_t)(j - 128) * 1024 + p0 + lane] = acc[jj];
        }
    }
    // ---- halo xi (3 cols x 128 j) via lane=c reduction, or zero-fill ----
    if (ptile > 0) {
        for (int jj = 0; jj < 32; ++jj) {
            int j = wq * 32 + jj;                        // uniform
            float wv = win[(size_t)j * 64 + lane];       // coalesced
            float a0 = wv * sX[lane * 68 + 64];
            float a1 = wv * sX[lane * 68 + 65];
            float a2v = wv * sX[lane * 68 + 66];
#pragma unroll
            for (int off = 1; off < 64; off <<= 1) {
                a0  += __shfl_xor(a0,  off);
                a1  += __shfl_xor(a1,  off);
                a2v += __shfl_xor(a2v, off);
            }
            if (lane == 0) {
                sXI[j * 68 + 64] = a0;
                sXI[j * 68 + 65] = a1;
                sXI[j * 68 + 66] = a2v;
            }
        }
    } else {
#pragma unroll
        for (int k = 0; k < 2; ++k) {
            int d = (tid >> 2) + k * 64, hc = tid & 3;
            if (hc < 3) sXI[d * 68 + 64 + hc] = 0.f;
        }
    }
    __syncthreads();
    // ---- conv4 + SiLU in place; store xc to global ----
    float* xcg = ws + O_XC + (size_t)seq * 131072;
    int c3 = (lane >= 3) ? lane - 3 : 64 + lane;
    int c2i = (lane >= 2) ? lane - 2 : 65 + lane;
    int c1 = (lane >= 1) ? lane - 1 : 66;
    for (int dd = 0; dd < 32; ++dd) {
        int d = wq * 32 + dd;                            // uniform
        float4 wc = *(const float4*)&wconv[d * 4];       // scalar
        int base = d * 68;
        float v = bconv[d] + sXI[base + c3]*wc.x + sXI[base + c2i]*wc.y
                           + sXI[base + c1]*wc.z + sXI[base + lane]*wc.w;
        v = v * sigmoidf_(v);
        sXI[base + lane] = v;
        xcg[(size_t)d * 1024 + p0 + lane] = v;
    }
    __syncthreads();
    // ---- x-proj: 9 j per wave (K=128) ----
    float acc9[9];
#pragma unroll
    for (int jj = 0; jj < 9; ++jj) acc9[jj] = 0.f;
    int jb9 = wq * 9;                                    // uniform
#pragma unroll 2
    for (int c4 = 0; c4 < 32; ++c4) {
        float xv0 = sXI[(c4*4+0) * 68 + lane];
        float xv1 = sXI[(c4*4+1) * 68 + lane];
        float xv2 = sXI[(c4*4+2) * 68 + lane];
        float xv3 = sXI[(c4*4+3) * 68 + lane];
#pragma unroll
        for (int jj = 0; jj < 9; ++jj) {
            float4 w4 = *(const float4*)&wxp[(size_t)(jb9 + jj) * 128 + c4 * 4];
            acc9[jj] += xv0*w4.x + xv1*w4.y + xv2*w4.z + xv3*w4.w;
        }
    }
#pragma unroll
    for (int jj = 0; jj < 9; ++jj) {
        int j = jb9 + jj;                                // uniform
        float v = acc9[jj];
        if (j < 4)       ws[O_DTP + ((size_t)seq * 4 + j) * 1024 + p0 + lane] = v;
        else if (j < 20) ws[O_BM + (size_t)seq * 16384 + (size_t)(j - 4)  * 1024 + p0 + lane] = v;
        else             ws[O_CM + (size_t)seq * 16384 + (size_t)(j - 20) * 1024 + p0 + lane] = v;
    }
}

// ================= k3: chunk-parallel scan, 32 chunks x 32 steps =================
__device__ __forceinline__ void k3_a2(const float* alog, int d0, int s0, float* a2) {
    float4 a0 = *(const float4*)(alog + d0 * 16 + s0);
    float4 a1 = *(const float4*)(alog + (d0 + 1) * 16 + s0);
    a2[0] = -fexp2(a0.x * L2E) * L2E; a2[1] = -fexp2(a0.y * L2E) * L2E;
    a2[2] = -fexp2(a0.z * L2E) * L2E; a2[3] = -fexp2(a0.w * L2E) * L2E;
    a2[4] = -fexp2(a1.x * L2E) * L2E; a2[5] = -fexp2(a1.y * L2E) * L2E;
    a2[6] = -fexp2(a1.z * L2E) * L2E; a2[7] = -fexp2(a1.w * L2E) * L2E;
}

// phase A: local scan (h0=0); emit per-chunk P = exp2(a2*sum_dt) and end E
__global__ __launch_bounds__(256) void k3a_scan(const float* __restrict__ wdt,
                                                const float* __restrict__ bdt,
                                                const float* __restrict__ alog,
                                                float* __restrict__ ws)
{
    __shared__ float sXC[128 * 33];
    __shared__ __align__(16) float sB[32 * 16];
    __shared__ __align__(16) float sDtp[32 * 4];
    int bid = blockIdx.x;
    int seq = bid >> 5, ch = bid & 31;
    int lb = ch * 32;
    int tid = threadIdx.x;
    int d0 = (tid >> 2) * 2, s0 = (tid & 3) * 4;

    float4 wdt0 = *(const float4*)&wdt[d0 * 4];
    float4 wdt1 = *(const float4*)&wdt[(d0 + 1) * 4];
    float bdt0 = bdt[d0], bdt1 = bdt[d0 + 1];
    float a2[8];
    k3_a2(alog, d0, s0, a2);

    const float* xcg = ws + O_XC + (size_t)seq * 131072;
    const float* Bmg = ws + O_BM + (size_t)seq * 16384;
#pragma unroll
    for (int k = 0; k < 16; ++k) {
        int i = tid + k * 256;
        int d = i >> 5, li = i & 31;
        sXC[d * 33 + li] = xcg[(size_t)d * 1024 + lb + li];
    }
#pragma unroll
    for (int k = 0; k < 2; ++k) {
        int i = tid + k * 256;
        int s = i >> 5, li = i & 31;
        sB[li * 16 + s] = Bmg[(size_t)s * 1024 + lb + li];
    }
    if (tid < 128) {
        int li = tid >> 2, j = tid & 3;
        sDtp[li * 4 + j] = ws[O_DTP + ((size_t)seq * 4 + j) * 1024 + lb + li];
    }
    __syncthreads();

    float h[8];
#pragma unroll
    for (int i = 0; i < 8; ++i) h[i] = 0.f;
    float sdt0 = 0.f, sdt1 = 0.f;
    for (int li = 0; li < 32; ++li) {
        float4 q = *(const float4*)&sDtp[li * 4];
        float dt0 = softplusf_(bdt0 + q.x*wdt0.x + q.y*wdt0.y + q.z*wdt0.z + q.w*wdt0.w);
        float dt1 = softplusf_(bdt1 + q.x*wdt1.x + q.y*wdt1.y + q.z*wdt1.z + q.w*wdt1.w);
        float dx0 = dt0 * sXC[d0 * 33 + li], dx1 = dt1 * sXC[(d0 + 1) * 33 + li];
        float4 Bv = *(const float4*)&sB[li * 16 + s0];
        float bv[4] = {Bv.x, Bv.y, Bv.z, Bv.w};
        sdt0 += dt0; sdt1 += dt1;
#pragma unroll
        for (int ss = 0; ss < 4; ++ss) {
            h[ss]     = fexp2(dt0 * a2[ss])     * h[ss]     + dx0 * bv[ss];
            h[4 + ss] = fexp2(dt1 * a2[4 + ss]) * h[4 + ss] + dx1 * bv[ss];
        }
    }
    float* hp = ws + O_HP + (size_t)(seq * 32 + ch) * 4096;
#pragma unroll
    for (int ss = 0; ss < 4; ++ss) {
        hp[d0 * 16 + s0 + ss]              = fexp2(a2[ss] * sdt0);
        hp[(d0 + 1) * 16 + s0 + ss]        = fexp2(a2[4 + ss] * sdt1);
        hp[2048 + d0 * 16 + s0 + ss]       = h[ss];
        hp[2048 + (d0 + 1) * 16 + s0 + ss] = h[4 + ss];
    }
}

// phase B: per-seq sequential prefix compose; h_init overwrites P slot
__global__ __launch_bounds__(256) void k3b_compose(float* __restrict__ ws)
{
    int seq = blockIdx.x;
    int tid = threadIdx.x;
    int d0 = (tid >> 2) * 2, s0 = (tid & 3) * 4;
    int i0 = d0 * 16 + s0, i1 = (d0 + 1) * 16 + s0;
    float h[8];
#pragma unroll
    for (int i = 0; i < 8; ++i) h[i] = 0.f;
    float* hpb = ws + O_HP + (size_t)seq * 32 * 4096;
    for (int c = 0; c < 32; ++c) {
        float* hp = hpb + (size_t)c * 4096;
        float4 P0 = *(const float4*)&hp[i0];
        float4 P1 = *(const float4*)&hp[i1];
        float4 E0 = *(const float4*)&hp[2048 + i0];
        float4 E1 = *(const float4*)&hp[2048 + i1];
        *(float4*)&hp[i0] = make_float4(h[0], h[1], h[2], h[3]);
        *(float4*)&hp[i1] = make_float4(h[4], h[5], h[6], h[7]);
        h[0] = P0.x * h[0] + E0.x; h[1] = P0.y * h[1] + E0.y;
        h[2] = P0.z * h[2] + E0.z; h[3] = P0.w * h[3] + E0.w;
        h[4] = P1.x * h[4] + E1.x; h[5] = P1.y * h[5] + E1.y;
        h[6] = P1.z * h[6] + E1.z; h[7] = P1.w * h[7] + E1.w;
    }
}

// ================= kC: rescan + gate + out-proj + skip (fused) =================
// grid 1024 = 32 seq * 32 chunk; block 256.
__global__ __launch_bounds__(256) void kC_back(
    const float* __restrict__ x0, const float* __restrict__ x1,
    const float* __restrict__ x2, const float* __restrict__ x3,
    const float* __restrict__ g1, const float* __restrict__ be1,
    const float* __restrict__ g2, const float* __restrict__ be2,
    const float* __restrict__ g3, const float* __restrict__ be3,
    const float* __restrict__ g4, const float* __restrict__ be4,
    const float* __restrict__ wdt, const float* __restrict__ bdt,
    const float* __restrict__ alog, const float* __restrict__ dpar,
    const float* __restrict__ woutp, const float* __restrict__ skipp,
    float* __restrict__ ws, float* __restrict__ out)
{
    __shared__ float sXC[128 * 33];   // xc, overwritten by gated g during scan
    __shared__ float sZ[128 * 33];
    __shared__ __align__(16) float sB[32 * 16];
    __shared__ __align__(16) float sC[32 * 16];
    __shared__ __align__(16) float sDtp[32 * 4];
    int bid = blockIdx.x;
    int seq = bid >> 5, ch = bid & 31;
    int branch = seq >> 3, b = seq & 7;
    int lb = ch * 32;
    int tid = threadIdx.x;
    int lane = tid & 63;
    int wq = uniform(tid >> 6);
    int sq = tid & 3;
    int d0 = (tid >> 2) * 2, s0 = sq * 4;

    float4 wdt0 = *(const float4*)&wdt[d0 * 4];
    float4 wdt1 = *(const float4*)&wdt[(d0 + 1) * 4];
    float bdt0 = bdt[d0], bdt1 = bdt[d0 + 1];
    float D0 = dpar[d0], D1 = dpar[d0 + 1];
    float a2[8];
    k3_a2(alog, d0, s0, a2);

    const float* xcg = ws + O_XC + (size_t)seq * 131072;
    const float* zzg = ws + O_Z  + (size_t)seq * 131072;
    const float* Bmg = ws + O_BM + (size_t)seq * 16384;
    const float* Cmg = ws + O_CM + (size_t)seq * 16384;
#pragma unroll
    for (int k = 0; k < 16; ++k) {
        int i = tid + k * 256;
        int d = i >> 5, li = i & 31;
        sXC[d * 33 + li] = xcg[(size_t)d * 1024 + lb + li];
        sZ [d * 33 + li] = zzg[(size_t)d * 1024 + lb + li];
    }
#pragma unroll
    for (int k = 0; k < 2; ++k) {
        int i = tid + k * 256;
        int s = i >> 5, li = i & 31;
        sB[li * 16 + s] = Bmg[(size_t)s * 1024 + lb + li];
        sC[li * 16 + s] = Cmg[(size_t)s * 1024 + lb + li];
    }
    if (tid < 128) {
        int li = tid >> 2, j = tid & 3;
        sDtp[li * 4 + j] = ws[O_DTP + ((size_t)seq * 4 + j) * 1024 + lb + li];
    }
    const float* hp = ws + O_HP + (size_t)(seq * 32 + ch) * 4096;
    float4 H0 = *(const float4*)&hp[d0 * 16 + s0];
    float4 H1 = *(const float4*)&hp[(d0 + 1) * 16 + s0];
    float h[8] = {H0.x, H0.y, H0.z, H0.w, H1.x, H1.y, H1.z, H1.w};
    __syncthreads();

    // ---- scan + in-loop gating; g overwrites sXC ----
    for (int li = 0; li < 32; ++li) {
        float4 q = *(const float4*)&sDtp[li * 4];
        float dt0 = softplusf_(bdt0 + q.x*wdt0.x + q.y*wdt0.y + q.z*wdt0.z + q.w*wdt0.w);
        float dt1 = softplusf_(bdt1 + q.x*wdt1.x + q.y*wdt1.y + q.z*wdt1.z + q.w*wdt1.w);
        float xc0 = sXC[d0 * 33 + li], xc1 = sXC[(d0 + 1) * 33 + li];
        float dx0 = dt0 * xc0, dx1 = dt1 * xc1;
        float4 Bv = *(const float4*)&sB[li * 16 + s0];
        float4 Cv = *(const float4*)&sC[li * 16 + s0];
        float bv[4] = {Bv.x, Bv.y, Bv.z, Bv.w};
        float cv[4] = {Cv.x, Cv.y, Cv.z, Cv.w};
        float acc0 = 0.f, acc1 = 0.f;
#pragma unroll
        for (int ss = 0; ss < 4; ++ss) {
            h[ss] = fexp2(dt0 * a2[ss]) * h[ss] + dx0 * bv[ss];
            acc0 += h[ss] * cv[ss];
            h[4 + ss] = fexp2(dt1 * a2[4 + ss]) * h[4 + ss] + dx1 * bv[ss];
            acc1 += h[4 + ss] * cv[ss];
        }
        acc0 += __shfl_xor(acc0, 1); acc0 += __shfl_xor(acc0, 2);
        acc1 += __shfl_xor(acc1, 1); acc1 += __shfl_xor(acc1, 2);
        if (sq == 0) {
            float z0 = sZ[d0 * 33 + li], z1 = sZ[(d0 + 1) * 33 + li];
            sXC[d0 * 33 + li]       = (acc0 + D0 * xc0) * (z0 * sigmoidf_(z0));
            sXC[(d0 + 1) * 33 + li] = (acc1 + D1 * xc1) * (z1 * sigmoidf_(z1));
        }
    }
    __syncthreads();

    // ---- out-proj GEMM 64c x 32col (K=128) + skip epilogue ----
    int col = lane & 31;             // lanes 32..63 duplicate (free 2-way LDS alias)
    int colg = lb + col;
    const float* xin = (branch==0)?x0:(branch==1)?x1:(branch==2)?x2:x3;
    const float* gam = (branch==0)?g1:(branch==1)?g2:(branch==2)?g3:g4;
    const float* bet = (branch==0)?be1:(branch==1)?be2:(branch==2)?be3:be4;
    const float* xb = xin + (size_t)b * 65536;
    float mean = ws[O_M  + (size_t)seq * 1024 + colg];
    float rs   = ws[O_RS + (size_t)seq * 1024 + colg];
    float skipv = skipp[0];
    for (int pass = 0; pass < 2; ++pass) {
        int c0 = wq * 16 + pass * 8;                     // uniform
        float acc8[8];
#pragma unroll
        for (int cc = 0; cc < 8; ++cc) acc8[cc] = 0.f;
#pragma unroll 2
        for (int d4 = 0; d4 < 32; ++d4) {
            float gv0 = sXC[(d4*4+0) * 33 + col];
            float gv1 = sXC[(d4*4+1) * 33 + col];
            float gv2 = sXC[(d4*4+2) * 33 + col];
            float gv3 = sXC[(d4*4+3) * 33 + col];
#pragma unroll
            for (int cc = 0; cc < 8; ++cc) {
                float4 w4 = *(const float4*)&woutp[(size_t)(c0 + cc) * 128 + d4 * 4];
                acc8[cc] += gv0*w4.x + gv1*w4.y + gv2*w4.z + gv3*w4.w;
            }
        }
        if (lane < 32) {
#pragma unroll
            for (int cc = 0; cc < 8; ++cc) {
                int c = c0 + cc;                         // uniform
                float xv = xb[(size_t)c * 1024 + colg];
                float xn = (xv - mean) * rs * gam[c] + bet[c];
                out[((size_t)b * 256 + branch * 64 + c) * 1024 + colg] = acc8[cc] + skipv * xn;
            }
        }
    }
}

// ---------------- launch ----------------
extern "C" void kernel_launch(void* const* d_in, const int* in_sizes, int n_in,
                              void* d_out, int out_size, void* d_ws, size_t ws_size,
                              hipStream_t stream) {
    float* ws = (float*)d_ws;
    auto f = [&](int i) { return (const float*)d_in[i]; };
    hipLaunchKernelGGL(kA_front, dim3(512), dim3(256), 0, stream,
        f(0), f(1), f(2), f(3), f(13),
        f(4), f(5), f(6), f(7), f(8), f(9), f(10), f(11),
        f(14), f(15), f(16), ws);
    hipLaunchKernelGGL(k3a_scan, dim3(1024), dim3(256), 0, stream, f(17), f(18), f(19), ws);
    hipLaunchKernelGGL(k3b_compose, dim3(32), dim3(256), 0, stream, ws);
    hipLaunchKernelGGL(kC_back, dim3(1024), dim3(256), 0, stream,
        f(0), f(1), f(2), f(3),
        f(4), f(5), f(6), f(7), f(8), f(9), f(10), f(11),
        f(17), f(18), f(19), f(20), f(21), f(12),
        ws, (float*)d_out);
}